// Round 5
// baseline (3098.767 us; speedup 1.0000x reference)
//
#include <hip/hip_runtime.h>
#include <math.h>

// ---------------------------------------------------------------------------
// AttentiveFP forward, MI355X. Round 2 source (resubmit x3; R2-R4 infra-failed).
// Key idea: LDS reads must be wave-uniform broadcasts (one LDS pipe per CU,
// ~24:1 FMA:b128 needed to be VALU-bound). Each thread: 8 rows x 4 cols;
// X/H rows broadcast from LDS, weights streamed from global (L2-resident,
// k-contiguous). GEMM weights pre-transposed once into ws.
// ---------------------------------------------------------------------------

__device__ __forceinline__ float leaky01(float v) { return v > 0.f ? v : 0.01f * v; }
__device__ __forceinline__ float eluf(float v)    { return v > 0.f ? v : (expf(v) - 1.f); }
__device__ __forceinline__ float sigmf(float v)   { return 1.f / (1.f + expf(-v)); }

// ------------------------------ CSR build ----------------------------------

__global__ void k_hist(const int* __restrict__ idx, int* __restrict__ cnt, int n) {
  int i = blockIdx.x * 256 + threadIdx.x;
  if (i < n) atomicAdd(&cnt[idx[i]], 1);
}

__global__ void k_scan1(const int* __restrict__ in, int* __restrict__ out1,
                        int* __restrict__ bsums, int n) {
  __shared__ int s[256];
  int t = threadIdx.x;
  int i = blockIdx.x * 256 + t;
  int v = (i < n) ? in[i] : 0;
  s[t] = v;
  __syncthreads();
  for (int off = 1; off < 256; off <<= 1) {
    int tv = (t >= off) ? s[t - off] : 0;
    __syncthreads();
    s[t] += tv;
    __syncthreads();
  }
  if (i < n) out1[i] = s[t];
  if (t == 255) bsums[blockIdx.x] = s[255];
}

__global__ void k_scan2(int* __restrict__ bsums, int nb) {
  __shared__ int s[256];
  int t = threadIdx.x;
  int v = (t < nb) ? bsums[t] : 0;
  s[t] = v;
  __syncthreads();
  for (int off = 1; off < 256; off <<= 1) {
    int tv = (t >= off) ? s[t - off] : 0;
    __syncthreads();
    s[t] += tv;
    __syncthreads();
  }
  if (t < nb) bsums[t] = s[t];
}

__global__ void k_scan3(int* __restrict__ out1, const int* __restrict__ bsums, int n) {
  int b = blockIdx.x;
  if (b == 0) return;
  int i = b * 256 + threadIdx.x;
  if (i < n) out1[i] += bsums[b - 1];
}

__global__ void k_scatter(const int* __restrict__ ei, const int* __restrict__ off,
                          int* __restrict__ cur, int* __restrict__ csrc,
                          int* __restrict__ ceid, int E) {
  int e = blockIdx.x * 256 + threadIdx.x;
  if (e >= E) return;
  int s = ei[e];
  int d = ei[E + e];
  int pos = off[d] + atomicAdd(&cur[d], 1);
  csrc[pos] = s;
  ceid[pos] = e;
}

// ------------------------------ weight transpose ---------------------------
// 7 matrices [128][128] k-major -> [out][k] row-major in ws.

__global__ void k_tr7(const float* __restrict__ s0, const float* __restrict__ s1,
                      const float* __restrict__ s2, const float* __restrict__ s3,
                      const float* __restrict__ s4, const float* __restrict__ s5,
                      const float* __restrict__ s6, float* __restrict__ dst) {
  __shared__ float tile[128][129];
  const float* s;
  switch (blockIdx.x) {
    case 0: s = s0; break; case 1: s = s1; break; case 2: s = s2; break;
    case 3: s = s3; break; case 4: s = s4; break; case 5: s = s5; break;
    default: s = s6; break;
  }
  float* d = dst + (size_t)blockIdx.x * 16384;
  int t = threadIdx.x;
  #pragma unroll
  for (int i = 0; i < 64; ++i) {
    int idx = t + 256 * i;
    tile[idx >> 7][idx & 127] = s[idx];
  }
  __syncthreads();
  #pragma unroll
  for (int i = 0; i < 64; ++i) {
    int idx = t + 256 * i;
    d[idx] = tile[idx & 127][idx >> 7];
  }
}

// ------------------------------ GEMM (K=128, Nout=128) ---------------------
// C = act(A @ WT^T + bias), WT [128 out][128 k] row-major.
// 64 rows/block, 256 threads; thread tile 8 rows x 4 cols (j, j+32, j+64, j+96).
// A rows broadcast from LDS (wave-uniform), weights from global (L1/L2).

__launch_bounds__(256)
__global__ void k_gemmT(const float* __restrict__ A, const float* __restrict__ WT,
                        const float* __restrict__ bias, float* __restrict__ C,
                        int M, int act) {
  __shared__ float As[64][132];
  int t = threadIdx.x;
  int m0 = blockIdx.x * 64;
  #pragma unroll
  for (int i = 0; i < 8; ++i) {
    int f = t + i * 256;
    int row = f >> 5, kf = f & 31;
    int gr = m0 + row;
    float4 v = make_float4(0.f, 0.f, 0.f, 0.f);
    if (gr < M) v = *(const float4*)(A + (size_t)gr * 128 + kf * 4);
    *(float4*)(&As[row][kf * 4]) = v;
  }
  __syncthreads();

  int j = t & 31;
  int rbase = (t >> 5) * 8;
  const float* w0 = WT + (size_t)j * 128;
  float acc[8][4] = {};
  for (int k = 0; k < 128; k += 4) {
    float4 w[4];
    #pragma unroll
    for (int q = 0; q < 4; ++q) w[q] = *(const float4*)(w0 + (size_t)q * 4096 + k);
    #pragma unroll
    for (int r = 0; r < 8; ++r) {
      float4 a = *(const float4*)(&As[rbase + r][k]);
      #pragma unroll
      for (int q = 0; q < 4; ++q)
        acc[r][q] += a.x * w[q].x + a.y * w[q].y + a.z * w[q].z + a.w * w[q].w;
    }
  }

  #pragma unroll
  for (int r = 0; r < 8; ++r) {
    int gr = m0 + rbase + r;
    if (gr >= M) continue;
    #pragma unroll
    for (int q = 0; q < 4; ++q) {
      int n = j + 32 * q;
      float v = acc[r][q];
      if (bias) v += bias[n];
      if (act == 1) v = leaky01(v);
      else if (act == 2) v = fmaxf(v, 0.f);
      else if (act == 3) v = eluf(v);
      C[(size_t)gr * 128 + n] = v;
    }
  }
}

// ------------------------------ fused GRU ----------------------------------
// out = relu(gru(inp, hid)). Wi/Wh [384,128] row-major ([out,k] — k contiguous).
// 64 rows/block, 256 threads, thread tile 8 rows x 4 cols; X/H staged to LDS
// once, broadcast-read across all 3 gate chunks.

__launch_bounds__(256, 2)
__global__ void k_gru(const float* __restrict__ inp, const float* __restrict__ hid,
                      const float* __restrict__ Wi, const float* __restrict__ bi,
                      const float* __restrict__ Wh, const float* __restrict__ bh,
                      float* __restrict__ out, int M) {
  __shared__ float inS[64][132];
  __shared__ float hidS[64][132];
  int t = threadIdx.x;
  int m0 = blockIdx.x * 64;
  #pragma unroll
  for (int i = 0; i < 8; ++i) {
    int f = t + i * 256;
    int row = f >> 5, kf = f & 31;
    int gr = m0 + row;
    float4 vi = make_float4(0.f, 0.f, 0.f, 0.f), vh = vi;
    if (gr < M) {
      vi = *(const float4*)(inp + (size_t)gr * 128 + kf * 4);
      vh = *(const float4*)(hid + (size_t)gr * 128 + kf * 4);
    }
    *(float4*)(&inS[row][kf * 4]) = vi;
    *(float4*)(&hidS[row][kf * 4]) = vh;
  }
  __syncthreads();

  int j = t & 31;
  int rbase = (t >> 5) * 8;
  float aI[8][4], aH[8][4], rv[8][4], zv[8][4];

  auto dochunk = [&](int c) {
    const float* wi0 = Wi + (size_t)(c * 128 + j) * 128;
    const float* wh0 = Wh + (size_t)(c * 128 + j) * 128;
    #pragma unroll
    for (int r = 0; r < 8; ++r)
      #pragma unroll
      for (int q = 0; q < 4; ++q) { aI[r][q] = 0.f; aH[r][q] = 0.f; }
    for (int k = 0; k < 128; k += 4) {
      float4 wi4[4], wh4[4];
      #pragma unroll
      for (int q = 0; q < 4; ++q) {
        wi4[q] = *(const float4*)(wi0 + (size_t)q * 4096 + k);
        wh4[q] = *(const float4*)(wh0 + (size_t)q * 4096 + k);
      }
      #pragma unroll
      for (int r = 0; r < 8; ++r) {
        float4 x4 = *(const float4*)(&inS[rbase + r][k]);
        float4 h4 = *(const float4*)(&hidS[rbase + r][k]);
        #pragma unroll
        for (int q = 0; q < 4; ++q) {
          aI[r][q] += x4.x * wi4[q].x + x4.y * wi4[q].y + x4.z * wi4[q].z + x4.w * wi4[q].w;
          aH[r][q] += h4.x * wh4[q].x + h4.y * wh4[q].y + h4.z * wh4[q].z + h4.w * wh4[q].w;
        }
      }
    }
  };

  dochunk(0);
  {
    float bI[4], bH[4];
    #pragma unroll
    for (int q = 0; q < 4; ++q) { bI[q] = bi[j + 32 * q]; bH[q] = bh[j + 32 * q]; }
    #pragma unroll
    for (int r = 0; r < 8; ++r)
      #pragma unroll
      for (int q = 0; q < 4; ++q) rv[r][q] = sigmf(aI[r][q] + bI[q] + aH[r][q] + bH[q]);
  }
  dochunk(1);
  {
    float bI[4], bH[4];
    #pragma unroll
    for (int q = 0; q < 4; ++q) { bI[q] = bi[128 + j + 32 * q]; bH[q] = bh[128 + j + 32 * q]; }
    #pragma unroll
    for (int r = 0; r < 8; ++r)
      #pragma unroll
      for (int q = 0; q < 4; ++q) zv[r][q] = sigmf(aI[r][q] + bI[q] + aH[r][q] + bH[q]);
  }
  dochunk(2);
  {
    float bI[4], bH[4];
    #pragma unroll
    for (int q = 0; q < 4; ++q) { bI[q] = bi[256 + j + 32 * q]; bH[q] = bh[256 + j + 32 * q]; }
    #pragma unroll
    for (int r = 0; r < 8; ++r) {
      int gr = m0 + rbase + r;
      if (gr >= M) continue;
      #pragma unroll
      for (int q = 0; q < 4; ++q) {
        int n = j + 32 * q;
        float nv = tanhf(aI[r][q] + bI[q] + rv[r][q] * (aH[r][q] + bH[q]));
        float hv = hidS[rbase + r][n];
        float o = (1.f - zv[r][q]) * nv + zv[r][q] * hv;
        out[(size_t)gr * 128 + n] = fmaxf(o, 0.f);
      }
    }
  }
}

// ------------------------------ matvec (1 or 2 vectors) --------------------

__global__ void k_matvec2(const float* __restrict__ A, const float* __restrict__ v1,
                          const float* __restrict__ v2, float* __restrict__ o1,
                          float* __restrict__ o2, int M) {
  int wid = (blockIdx.x * blockDim.x + threadIdx.x) >> 6;
  int lane = threadIdx.x & 63;
  if (wid >= M) return;
  const float* a = A + (size_t)wid * 128;
  float a0 = a[lane], a1 = a[lane + 64];
  float p1 = a0 * v1[lane] + a1 * v1[lane + 64];
  #pragma unroll
  for (int o = 32; o > 0; o >>= 1) p1 += __shfl_xor(p1, o, 64);
  if (lane == 0) o1[wid] = p1;
  if (v2) {
    float p2 = a0 * v2[lane] + a1 * v2[lane + 64];
    #pragma unroll
    for (int o = 32; o > 0; o >>= 1) p2 += __shfl_xor(p2, o, 64);
    if (lane == 0) o2[wid] = p2;
  }
}

// ------------------------------ GATEConv aggregate -------------------------

__global__ void k_conv_gate(const float* __restrict__ xg, const float* __restrict__ w128,
                            const float* __restrict__ attL, const float* __restrict__ xr,
                            const float* __restrict__ ea, const int* __restrict__ off,
                            const int* __restrict__ csrc, const int* __restrict__ ceid,
                            float* __restrict__ agg, int N) {
  int wid = (blockIdx.x * blockDim.x + threadIdx.x) >> 6;
  if (wid >= N) return;
  int lane = threadIdx.x & 63;
  int j0 = lane * 2;
  float aL0 = attL[j0], aL1 = attL[j0 + 1];
  float w0 = w128[j0], w1 = w128[j0 + 1];
  float xrn = xr[wid];
  float m = -INFINITY, s = 0.f, acc0 = 0.f, acc1 = 0.f;
  int e0 = off[wid], e1 = off[wid + 1];
  for (int e = e0; e < e1; ++e) {
    int src = csrc[e];
    float eav = ea[ceid[e]];
    float2 xv = *(const float2*)(xg + (size_t)src * 128 + j0);
    float h0 = leaky01(xv.x + eav * w0);
    float h1 = leaky01(xv.y + eav * w1);
    float part = h0 * aL0 + h1 * aL1;
    #pragma unroll
    for (int o = 32; o > 0; o >>= 1) part += __shfl_xor(part, o, 64);
    float logit = leaky01(part + xrn);
    float mn = fmaxf(m, logit);
    float sc = expf(m - mn);
    float p = expf(logit - mn);
    s = s * sc + p;
    acc0 = acc0 * sc + p * h0;
    acc1 = acc1 * sc + p * h1;
    m = mn;
  }
  float r = 1.f / (s + 1e-16f);
  float2 res = make_float2(acc0 * r, acc1 * r);
  *(float2*)(agg + (size_t)wid * 128 + j0) = res;
}

// ------------------------------ GATConv ------------------------------------

__global__ void k_conv_gat(const float* __restrict__ hs, const float* __restrict__ as_,
                           const float* __restrict__ ad_, const float* __restrict__ bcl,
                           const int* __restrict__ off, const int* __restrict__ csrc,
                           float* __restrict__ hout, int N) {
  int wid = (blockIdx.x * blockDim.x + threadIdx.x) >> 6;
  if (wid >= N) return;
  int lane = threadIdx.x & 63;
  int j0 = lane * 2;
  float adn = ad_[wid];
  float m = -INFINITY, s = 0.f, acc0 = 0.f, acc1 = 0.f;
  int e0 = off[wid], e1 = off[wid + 1];
  for (int e = e0; e < e1; ++e) {
    int src = csrc[e];
    float logit = leaky01(as_[src] + adn);
    float mn = fmaxf(m, logit);
    float sc = expf(m - mn);
    float p = expf(logit - mn);
    float2 hv = *(const float2*)(hs + (size_t)src * 128 + j0);
    s = s * sc + p;
    acc0 = acc0 * sc + p * hv.x;
    acc1 = acc1 * sc + p * hv.y;
    m = mn;
  }
  float r = 1.f / (s + 1e-16f);
  hout[(size_t)wid * 128 + j0]     = eluf(acc0 * r + bcl[j0]);
  hout[(size_t)wid * 128 + j0 + 1] = eluf(acc1 * r + bcl[j0 + 1]);
}

// ------------------------------ graph pooling ------------------------------

__global__ void k_pool(const float* __restrict__ X, const int* __restrict__ goff,
                       float* __restrict__ outb, int G) {
  int wid = (blockIdx.x * blockDim.x + threadIdx.x) >> 6;
  if (wid >= G) return;
  int lane = threadIdx.x & 63;
  int j0 = lane * 2;
  float s0 = 0.f, s1 = 0.f;
  int n0 = goff[wid], n1 = goff[wid + 1];
  for (int n = n0; n < n1; ++n) {
    float2 v = *(const float2*)(X + (size_t)n * 128 + j0);
    s0 += v.x;
    s1 += v.y;
  }
  outb[(size_t)wid * 128 + j0]     = fmaxf(s0, 0.f);
  outb[(size_t)wid * 128 + j0 + 1] = fmaxf(s1, 0.f);
}

// ------------------------------ molecule conv ------------------------------

__global__ void k_conv_mol(const float* __restrict__ hsm, const float* __restrict__ asrc,
                           const float* __restrict__ adg, const float* __restrict__ bm,
                           const int* __restrict__ goff, float* __restrict__ hout, int G) {
  int wid = (blockIdx.x * blockDim.x + threadIdx.x) >> 6;
  if (wid >= G) return;
  int lane = threadIdx.x & 63;
  int j0 = lane * 2;
  float adn = adg[wid];
  float m = -INFINITY, s = 0.f, acc0 = 0.f, acc1 = 0.f;
  int n0 = goff[wid], n1 = goff[wid + 1];
  for (int n = n0; n < n1; ++n) {
    float logit = leaky01(asrc[n] + adn);
    float mn = fmaxf(m, logit);
    float sc = expf(m - mn);
    float p = expf(logit - mn);
    float2 hv = *(const float2*)(hsm + (size_t)n * 128 + j0);
    s = s * sc + p;
    acc0 = acc0 * sc + p * hv.x;
    acc1 = acc1 * sc + p * hv.y;
    m = mn;
  }
  float r = 1.f / (s + 1e-16f);
  hout[(size_t)wid * 128 + j0]     = eluf(acc0 * r + bm[j0]);
  hout[(size_t)wid * 128 + j0 + 1] = eluf(acc1 * r + bm[j0 + 1]);
}

// ------------------------------ final head ---------------------------------

__global__ void k_final(const float* __restrict__ outb, const float* __restrict__ W2,
                        const float* __restrict__ b2, const float* __restrict__ Wp1,
                        const float* __restrict__ bp1, const float* __restrict__ Wp2,
                        const float* __restrict__ bp2, float* __restrict__ y, int G) {
  int g = blockIdx.x * 256 + threadIdx.x;
  if (g >= G) return;
  const float* o = outb + (size_t)g * 128;
  float s0 = b2[0], s1 = b2[1];
  for (int k = 0; k < 128; ++k) {
    float v = o[k];
    s0 += v * W2[2 * k];
    s1 += v * W2[2 * k + 1];
  }
  float p = s0 * Wp1[0] + s1 * Wp1[1] + bp1[0];
  p = fmaxf(p, 0.f);
  y[g] = p * Wp2[0] + bp2[0];
}

// ---------------------------------------------------------------------------

extern "C" void kernel_launch(void* const* d_in, const int* in_sizes, int n_in,
                              void* d_out, int out_size, void* d_ws, size_t ws_size,
                              hipStream_t stream) {
  const int N = 50000, E = 800000, G = 1000, NL = 4;

  const float* x_in  = (const float*)d_in[0];
  const int*   ei    = (const int*)  d_in[1];
  const int*   batch = (const int*)  d_in[2];
  const float* eattr = (const float*)d_in[3];
  const float* W1    = (const float*)d_in[4];
  const float* b1    = (const float*)d_in[5];
  const float* Wg1   = (const float*)d_in[6];
  const float* attL  = (const float*)d_in[7];
  const float* attR  = (const float*)d_in[8];
  const float* Wg2   = (const float*)d_in[9];
  const float* bg    = (const float*)d_in[10];
  const float* gWi0  = (const float*)d_in[11];
  const float* gWh0  = (const float*)d_in[12];
  const float* gbi0  = (const float*)d_in[13];
  const float* gbh0  = (const float*)d_in[14];
  const float* Wc    = (const float*)d_in[15];
  const float* aS    = (const float*)d_in[16];
  const float* aD    = (const float*)d_in[17];
  const float* bc    = (const float*)d_in[18];
  const float* gWi   = (const float*)d_in[19];
  const float* gWh   = (const float*)d_in[20];
  const float* gbi   = (const float*)d_in[21];
  const float* gbh   = (const float*)d_in[22];
  const float* Wm    = (const float*)d_in[23];
  const float* aSm   = (const float*)d_in[24];
  const float* aDm   = (const float*)d_in[25];
  const float* bm    = (const float*)d_in[26];
  const float* mWi   = (const float*)d_in[27];
  const float* mWh   = (const float*)d_in[28];
  const float* mbi   = (const float*)d_in[29];
  const float* mbh   = (const float*)d_in[30];
  const float* W2    = (const float*)d_in[31];
  const float* b2    = (const float*)d_in[32];
  const float* Wp1   = (const float*)d_in[33];
  const float* bp1   = (const float*)d_in[34];
  const float* Wp2   = (const float*)d_in[35];
  const float* bp2   = (const float*)d_in[36];

  char* base = (char*)d_ws;
  size_t o = 0;
  auto alloc = [&](size_t bytes) -> char* {
    char* p = base + o;
    o += (bytes + 255) & ~(size_t)255;
    return p;
  };
  float* X    = (float*)alloc((size_t)N * 128 * 4);
  float* Hb   = (float*)alloc((size_t)N * 128 * 4);
  float* S    = (float*)alloc((size_t)N * 128 * 4);
  float* AGG  = (float*)alloc((size_t)N * 128 * 4);
  float* sc1  = (float*)alloc((size_t)N * 4);
  float* sc2  = (float*)alloc((size_t)N * 4);
  float* asrc = (float*)alloc((size_t)N * 4);
  float* OutB = (float*)alloc((size_t)G * 128 * 4);
  float* Hm   = (float*)alloc((size_t)G * 128 * 4);
  float* oWm  = (float*)alloc((size_t)G * 128 * 4);
  float* adg  = (float*)alloc((size_t)G * 4);
  float* WT   = (float*)alloc((size_t)7 * 16384 * 4);   // transposed weights
  int*   deg  = (int*)alloc((size_t)N * 4);
  int*   off  = (int*)alloc((size_t)(N + 1) * 4);
  int*   cur  = (int*)alloc((size_t)N * 4);
  int*   csrc = (int*)alloc((size_t)E * 4);
  int*   ceid = (int*)alloc((size_t)E * 4);
  int*   degG = (int*)alloc((size_t)G * 4);
  int*   goff = (int*)alloc((size_t)(G + 1) * 4);
  int*   bs   = (int*)alloc(256 * 4);
  if (o > ws_size) return;  // fail visibly

  hipMemsetAsync(deg, 0, (size_t)N * 4, stream);
  hipMemsetAsync(cur, 0, (size_t)N * 4, stream);
  hipMemsetAsync(degG, 0, (size_t)G * 4, stream);
  hipMemsetAsync(off, 0, 4, stream);
  hipMemsetAsync(goff, 0, 4, stream);

  int nb1 = (N + 255) / 256;
  int nbG = (G + 255) / 256;
  k_hist<<<(E + 255) / 256, 256, 0, stream>>>(ei + E, deg, E);
  k_scan1<<<nb1, 256, 0, stream>>>(deg, off + 1, bs, N);
  k_scan2<<<1, 256, 0, stream>>>(bs, nb1);
  k_scan3<<<nb1, 256, 0, stream>>>(off + 1, bs, N);
  k_scatter<<<(E + 255) / 256, 256, 0, stream>>>(ei, off, cur, csrc, ceid, E);
  k_hist<<<(N + 255) / 256, 256, 0, stream>>>(batch, degG, N);
  k_scan1<<<nbG, 256, 0, stream>>>(degG, goff + 1, bs, G);
  k_scan2<<<1, 256, 0, stream>>>(bs, nbG);
  k_scan3<<<nbG, 256, 0, stream>>>(goff + 1, bs, G);

  // transposed weights: [0]=W1 [1]=Wg1[:128] [2]=Wg2 [3..5]=Wc [6]=Wm
  k_tr7<<<7, 256, 0, stream>>>(W1, Wg1, Wg2, Wc, Wc + 16384, Wc + 32768, Wm, WT);
  float* W1T  = WT;
  float* Wg1T = WT + 16384;
  float* Wg2T = WT + 2 * 16384;
  float* WcT  = WT + 3 * 16384;
  float* WmT  = WT + 6 * 16384;

  auto gemm = [&](const float* A, const float* WTm, const float* bias, float* C,
                  int M, int act) {
    k_gemmT<<<(M + 63) / 64, 256, 0, stream>>>(A, WTm, bias, C, M, act);
  };
  auto gru = [&](const float* inp, const float* hid, const float* Wi_, const float* bi_,
                 const float* Wh_, const float* bh_, float* outp, int M) {
    k_gru<<<(M + 63) / 64, 256, 0, stream>>>(inp, hid, Wi_, bi_, Wh_, bh_, outp, M);
  };

  // lin1 + leaky
  gemm(x_in, W1T, b1, X, N, 1);

  // --- GATEConv ---
  gemm(X, Wg1T, nullptr, S, N, 0);                              // xg = X @ Wg1[:128]
  k_matvec2<<<(N + 3) / 4, 256, 0, stream>>>(X, attR, nullptr, sc1, nullptr, N);
  k_conv_gate<<<(N + 3) / 4, 256, 0, stream>>>(S, Wg1 + 128 * 128, attL, sc1, eattr,
                                               off, csrc, ceid, AGG, N);
  gemm(AGG, Wg2T, bg, Hb, N, 3);                                // elu(agg@Wg2+bg)
  gru(Hb, X, gWi0, gbi0, gWh0, gbh0, X, N);

  // --- GATConv layers ---
  for (int l = 0; l < NL - 1; ++l) {
    gemm(X, WcT + (size_t)l * 16384, nullptr, S, N, 0);         // hs
    k_matvec2<<<(N + 3) / 4, 256, 0, stream>>>(S, aS + l * 128, aD + l * 128, sc1, sc2, N);
    k_conv_gat<<<(N + 3) / 4, 256, 0, stream>>>(S, sc1, sc2, bc + l * 128, off, csrc, Hb, N);
    gru(Hb, X, gWi + (size_t)l * 384 * 128, gbi + l * 384,
        gWh + (size_t)l * 384 * 128, gbh + l * 384, X, N);
  }

  // --- molecule phase ---
  k_pool<<<(G + 3) / 4, 256, 0, stream>>>(X, goff, OutB, G);
  gemm(X, WmT, nullptr, S, N, 0);                               // hsm
  k_matvec2<<<(N + 3) / 4, 256, 0, stream>>>(S, aSm, nullptr, asrc, nullptr, N);
  for (int t = 0; t < 2; ++t) {
    gemm(OutB, WmT, nullptr, oWm, G, 0);
    k_matvec2<<<(G + 3) / 4, 256, 0, stream>>>(oWm, aDm, nullptr, adg, nullptr, G);
    k_conv_mol<<<(G + 3) / 4, 256, 0, stream>>>(S, asrc, adg, bm, goff, Hm, G);
    gru(Hm, OutB, mWi, mbi, mWh, mbh, OutB, G);
  }

  k_final<<<(G + 255) / 256, 256, 0, stream>>>(OutB, W2, b2, Wp1, bp1, Wp2, bp2,
                                               (float*)d_out, G);
}